// Round 6
// baseline (56.129 us; speedup 1.0000x reference)
//
#include <hip/hip_runtime.h>
#include <hip/hip_bf16.h>
#include <stdint.h>

#define B_SZ    8
#define N_PTS   4096
#define C_IN    64
#define C_OUT   64
#define KNN     16
#define ROWS    (B_SZ * N_PTS)      // 32768

// ---------------------------------------------------------------------------
// Kernel 0: weight prep.  wcT[c][o] = W1[o][c]-W2[o][c],  w2T[c][o] = W2[o][c]
// ---------------------------------------------------------------------------
__global__ void wprep_kernel(const float* __restrict__ w,
                             float* __restrict__ wcT,
                             float* __restrict__ w2T)
{
    const int id = blockIdx.x * 256 + threadIdx.x;   // (c,o)
    if (id < C_IN * C_OUT) {
        const int c = id >> 6, o = id & 63;
        const float w1 = w[o * 128 + c];
        const float w2 = w[o * 128 + 64 + c];
        wcT[c * 64 + o] = w1 - w2;
        w2T[c * 64 + o] = w2;
    }
}

// ---------------------------------------------------------------------------
// Kernel 1: projections via SCALAR broadcast (no LDS).
//   waves 0,1: cbuf[r][o] = x[r]·(W1-W2)[o] + bias[o]       (fp32)
//   waves 2,3: nbuf[r][o] = x[r]·W2[o]                       (bf16)
// x row addresses are block/loop-uniform -> clang scalarizes to s_load;
// the FMA consumes the broadcast x value as its one SGPR operand.
// 64 weight floats/wave in VGPRs (no spill), 2 FMA chains/row fill the pipe.
// ---------------------------------------------------------------------------
#define PR 32   // rows per block

__global__ __launch_bounds__(256, 4) void proj_kernel(
    const float* __restrict__ x,
    const float* __restrict__ wcT,
    const float* __restrict__ w2T,
    const float* __restrict__ bias,
    float* __restrict__ cbuf,
    __hip_bfloat16* __restrict__ nbuf)
{
    const int t    = threadIdx.x;
    const int lane = t & 63;                // output channel o
    const int g    = t >> 6;                // wave 0..3

    const int batch = blockIdx.x & 7;       // XCD-affine
    const int chunk = blockIdx.x >> 3;      // 0..127
    const int r0 = batch * N_PTS + chunk * PR + (g & 1) * 16;

    const float* wt = (g < 2) ? wcT : w2T;
    float wreg[C_IN];
#pragma unroll
    for (int c = 0; c < C_IN; ++c)          // coalesced 256B loads
        wreg[c] = wt[c * 64 + lane];
    const float b0 = (g < 2) ? bias[lane] : 0.f;

    for (int i = 0; i < 16; ++i) {
        const int r = r0 + i;
        const float* xr = x + (size_t)r * C_IN;   // uniform base -> s_load
        float a0 = b0, a1 = 0.f;                  // 2 chains: hide FMA latency
#pragma unroll
        for (int j = 0; j < 32; ++j) {
            a0 = fmaf(xr[j],      wreg[j],      a0);
            a1 = fmaf(xr[32 + j], wreg[32 + j], a1);
        }
        const float a = a0 + a1;
        if (g < 2) cbuf[(size_t)r * C_OUT + lane] = a;          // 256B store
        else       nbuf[(size_t)r * C_OUT + lane] = __float2bfloat16(a);
    }
}

// ---------------------------------------------------------------------------
// Kernel 2: gather + max + relu + transposed store.
//   out[b][o][n] = relu( cbuf[b,n][o] + max_k nbuf[b, idx[b,n,k]][o] )
// nbuf is bf16: neighbor rows are 128B -> half the L2 gather traffic.
// 16 lanes x 8B cover a row; 4 rows per load instr. Max in fp32.
// ---------------------------------------------------------------------------
__global__ __launch_bounds__(256) void gather_max_kernel(
    const float* __restrict__ cbuf,
    const __hip_bfloat16* __restrict__ nbuf,
    const int* __restrict__ eidx,
    float* __restrict__ out)
{
    __shared__ float tile[64][65];

    const int t    = threadIdx.x;
    const int lane = t & 63;
    const int g    = t >> 6;                // wave 0..3
    const int b    = blockIdx.x & 7;        // batch == XCD
    const int tn   = blockIdx.x >> 3;       // 0..63
    const int n0   = tn * 64;

    const uint16_t* nb = (const uint16_t*)nbuf + (size_t)b * N_PTS * C_OUT;
    const int o4  = (lane & 15) * 4;        // first of 4 channels
    const int sub = lane >> 4;              // row within quad

    for (int i = 0; i < 4; ++i) {
        const int rbase = b * N_PTS + n0 + g * 16 + i * 4;
        int myidx = eidx[(size_t)rbase * KNN + lane] & (N_PTS - 1);

        const int r = rbase + sub;
        const float4 cv = *(const float4*)(cbuf + (size_t)r * C_OUT + o4);

        float m0 = -1e30f, m1 = -1e30f, m2 = -1e30f, m3 = -1e30f;
#pragma unroll
        for (int k = 0; k < KNN; ++k) {
            const int idx = __shfl(myidx, (lane & 48) | k);
            // 8B of bf16 = 4 channels; 4 rows per wave instruction
            const uint2 v = *(const uint2*)(nb + (size_t)idx * C_OUT + o4);
            m0 = fmaxf(m0, __uint_as_float(v.x << 16));
            m1 = fmaxf(m1, __uint_as_float(v.x & 0xffff0000u));
            m2 = fmaxf(m2, __uint_as_float(v.y << 16));
            m3 = fmaxf(m3, __uint_as_float(v.y & 0xffff0000u));
        }

        const int nl = g * 16 + i * 4 + sub;
        tile[nl][o4 + 0] = fmaxf(cv.x + m0, 0.f);   // relu(max)==max(relu)
        tile[nl][o4 + 1] = fmaxf(cv.y + m1, 0.f);
        tile[nl][o4 + 2] = fmaxf(cv.z + m2, 0.f);
        tile[nl][o4 + 3] = fmaxf(cv.w + m3, 0.f);
    }

    __syncthreads();

    float* ob = out + (size_t)b * C_OUT * N_PTS + n0;
#pragma unroll
    for (int j = 0; j < 16; ++j) {
        const int o = g * 16 + j;
        ob[(size_t)o * N_PTS + lane] = tile[lane][o];
    }
}

// ---------------------------------------------------------------------------
extern "C" void kernel_launch(void* const* d_in, const int* in_sizes, int n_in,
                              void* d_out, int out_size, void* d_ws, size_t ws_size,
                              hipStream_t stream)
{
    const float* x    = (const float*)d_in[0];
    const int*   eidx = (const int*)d_in[1];    // int64 in ref -> int32 here
    const float* w    = (const float*)d_in[2];  // (64, 128)
    const float* bias = (const float*)d_in[3];  // (64,)
    float*       out  = (float*)d_out;          // (8, 64, 64, 64) f32

    float*          cbuf = (float*)d_ws;                        // 8 MiB
    __hip_bfloat16* nbuf = (__hip_bfloat16*)(cbuf + (size_t)ROWS * C_OUT); // 4 MiB
    float*          wcT  = (float*)((char*)nbuf + (size_t)ROWS * C_OUT * 2);
    float*          w2T  = wcT + C_IN * C_OUT;

    wprep_kernel<<<16, 256, 0, stream>>>(w, wcT, w2T);
    proj_kernel<<<ROWS / PR, 256, 0, stream>>>(x, wcT, w2T, bias, cbuf, nbuf);
    gather_max_kernel<<<B_SZ * (N_PTS / 64), 256, 0, stream>>>(cbuf, nbuf, eidx, out);
}

// Round 7
// 36.000 us; speedup vs baseline: 1.5591x; 1.5591x over previous
//
#include <hip/hip_runtime.h>
#include <hip/hip_bf16.h>
#include <stdint.h>

#define B_SZ    8
#define N_PTS   4096
#define C_IN    64
#define C_OUT   64
#define KNN     16
#define ROWS    (B_SZ * N_PTS)      // 32768

// ---------------------------------------------------------------------------
// Kernel 0: weight prep.  wcT[c][o] = W1[o][c]-W2[o][c],  w2T[c][o] = W2[o][c]
// ---------------------------------------------------------------------------
__global__ void wprep_kernel(const float* __restrict__ w,
                             float* __restrict__ wcT,
                             float* __restrict__ w2T)
{
    const int id = blockIdx.x * 256 + threadIdx.x;   // (c,o)
    if (id < C_IN * C_OUT) {
        const int c = id >> 6, o = id & 63;
        const float w1 = w[o * 128 + c];
        const float w2 = w[o * 128 + 64 + c];
        wcT[c * 64 + o] = w1 - w2;
        w2T[c * 64 + o] = w2;
    }
}

// ---------------------------------------------------------------------------
// Kernel 1: projections via SCALAR broadcast.
// 128 threads = 2 waves; BOTH waves iterate the SAME 16 rows so the x-row
// address is a function of (blockIdx, i) ONLY -> provably uniform ->
// s_load_dwordx4 into SGPRs; FMA takes the broadcast as its SGPR operand.
//   wave 0: cbuf[r][o] = x[r]·(W1-W2)[o] + bias[o]   (fp32)
//   wave 1: nbuf[r][o] = x[r]·W2[o]                   (bf16)
// 64 weight floats per wave in VGPRs (compile-time indexed, no spill);
// two 32-FMA chains per row (issue rate == 4-cyc dep latency).
// ---------------------------------------------------------------------------
__global__ __launch_bounds__(128, 4) void proj_kernel(
    const float* __restrict__ x,
    const float* __restrict__ wcT,
    const float* __restrict__ w2T,
    const float* __restrict__ bias,
    float* __restrict__ cbuf,
    __hip_bfloat16* __restrict__ nbuf)
{
    const int lane = threadIdx.x & 63;      // output channel o
    const int g    = threadIdx.x >> 6;      // 0: cbuf, 1: nbuf

    const int batch = blockIdx.x & 7;       // XCD-affine
    const int chunk = blockIdx.x >> 3;      // 0..255
    const int r0    = batch * N_PTS + chunk * 16;   // uniform, no threadIdx

    const float* wt = g ? w2T : wcT;
    float wreg[C_IN];
#pragma unroll
    for (int c = 0; c < C_IN; ++c)          // coalesced 256B loads
        wreg[c] = wt[c * 64 + lane];
    const float b0 = g ? 0.f : bias[lane];

    for (int i = 0; i < 16; ++i) {
        const int r = r0 + i;               // uniform
        float a0 = b0, a1 = 0.f;            // 2 chains hide FMA latency
#pragma unroll
        for (int j = 0; j < 32; ++j) {
            a0 = fmaf(x[(size_t)r * C_IN + j],      wreg[j],      a0);
            a1 = fmaf(x[(size_t)r * C_IN + 32 + j], wreg[32 + j], a1);
        }
        const float a = a0 + a1;
        if (g == 0) cbuf[(size_t)r * C_OUT + lane] = a;          // 256B store
        else        nbuf[(size_t)r * C_OUT + lane] = __float2bfloat16(a);
    }
}

// ---------------------------------------------------------------------------
// Kernel 2: gather + max + relu + transposed store (unchanged).
//   out[b][o][n] = relu( cbuf[b,n][o] + max_k nbuf[b, idx[b,n,k]][o] )
// nbuf is bf16: neighbor rows are 128B -> half the L2 gather traffic.
// ---------------------------------------------------------------------------
__global__ __launch_bounds__(256) void gather_max_kernel(
    const float* __restrict__ cbuf,
    const __hip_bfloat16* __restrict__ nbuf,
    const int* __restrict__ eidx,
    float* __restrict__ out)
{
    __shared__ float tile[64][65];

    const int t    = threadIdx.x;
    const int lane = t & 63;
    const int g    = t >> 6;                // wave 0..3
    const int b    = blockIdx.x & 7;        // batch == XCD
    const int tn   = blockIdx.x >> 3;       // 0..63
    const int n0   = tn * 64;

    const uint16_t* nb = (const uint16_t*)nbuf + (size_t)b * N_PTS * C_OUT;
    const int o4  = (lane & 15) * 4;        // first of 4 channels
    const int sub = lane >> 4;              // row within quad

    for (int i = 0; i < 4; ++i) {
        const int rbase = b * N_PTS + n0 + g * 16 + i * 4;
        int myidx = eidx[(size_t)rbase * KNN + lane] & (N_PTS - 1);

        const int r = rbase + sub;
        const float4 cv = *(const float4*)(cbuf + (size_t)r * C_OUT + o4);

        float m0 = -1e30f, m1 = -1e30f, m2 = -1e30f, m3 = -1e30f;
#pragma unroll
        for (int k = 0; k < KNN; ++k) {
            const int idx = __shfl(myidx, (lane & 48) | k);
            const uint2 v = *(const uint2*)(nb + (size_t)idx * C_OUT + o4);
            m0 = fmaxf(m0, __uint_as_float(v.x << 16));
            m1 = fmaxf(m1, __uint_as_float(v.x & 0xffff0000u));
            m2 = fmaxf(m2, __uint_as_float(v.y << 16));
            m3 = fmaxf(m3, __uint_as_float(v.y & 0xffff0000u));
        }

        const int nl = g * 16 + i * 4 + sub;
        tile[nl][o4 + 0] = fmaxf(cv.x + m0, 0.f);   // relu(max)==max(relu)
        tile[nl][o4 + 1] = fmaxf(cv.y + m1, 0.f);
        tile[nl][o4 + 2] = fmaxf(cv.z + m2, 0.f);
        tile[nl][o4 + 3] = fmaxf(cv.w + m3, 0.f);
    }

    __syncthreads();

    float* ob = out + (size_t)b * C_OUT * N_PTS + n0;
#pragma unroll
    for (int j = 0; j < 16; ++j) {
        const int o = g * 16 + j;
        ob[(size_t)o * N_PTS + lane] = tile[lane][o];
    }
}

// ---------------------------------------------------------------------------
extern "C" void kernel_launch(void* const* d_in, const int* in_sizes, int n_in,
                              void* d_out, int out_size, void* d_ws, size_t ws_size,
                              hipStream_t stream)
{
    const float* x    = (const float*)d_in[0];
    const int*   eidx = (const int*)d_in[1];    // int64 in ref -> int32 here
    const float* w    = (const float*)d_in[2];  // (64, 128)
    const float* bias = (const float*)d_in[3];  // (64,)
    float*       out  = (float*)d_out;          // (8, 64, 64, 64) f32

    float*          cbuf = (float*)d_ws;                                   // 8 MiB
    __hip_bfloat16* nbuf = (__hip_bfloat16*)(cbuf + (size_t)ROWS * C_OUT); // 4 MiB
    float*          wcT  = (float*)((char*)nbuf + (size_t)ROWS * C_OUT * 2);
    float*          w2T  = wcT + C_IN * C_OUT;

    wprep_kernel<<<16, 256, 0, stream>>>(w, wcT, w2T);
    proj_kernel<<<ROWS / 16, 128, 0, stream>>>(x, wcT, w2T, bias, cbuf, nbuf);
    gather_max_kernel<<<B_SZ * (N_PTS / 64), 256, 0, stream>>>(cbuf, nbuf, eidx, out);
}

// Round 8
// 29.273 us; speedup vs baseline: 1.9174x; 1.2298x over previous
//
#include <hip/hip_runtime.h>
#include <hip/hip_bf16.h>
#include <stdint.h>

#define B_SZ    8
#define N_PTS   4096
#define C_IN    64
#define C_OUT   64
#define KNN     16
#define ROWS    (B_SZ * N_PTS)      // 32768

typedef __attribute__((ext_vector_type(8))) short v8s;   // 8 bf16 (4 VGPR)
typedef __attribute__((ext_vector_type(4))) float v4f;   // MFMA acc

__device__ inline unsigned short f2bf(float f) {         // RNE f32->bf16
    unsigned int u = __float_as_uint(f);
    return (unsigned short)((u + 0x7FFFu + ((u >> 16) & 1u)) >> 16);
}

// ---------------------------------------------------------------------------
// Kernel 0: pack combined weights B[k][col] (64x128) into MFMA B-fragment
// order: frag (ct,ks,lane) holds cols ct*16+(lane&15), k = ks*32+8*(lane>>4)+j.
//   col <  64: B[k][col] = W1[col][k] - W2[col][k]
//   col >= 64: B[k][col] = W2[col-64][k]
// ---------------------------------------------------------------------------
__global__ void wprep_kernel(const float* __restrict__ w, v8s* __restrict__ wfrag)
{
    const int tid = blockIdx.x * 256 + threadIdx.x;      // 0..1023
    if (tid >= 1024) return;
    const int lane = tid & 63;
    const int ks   = (tid >> 6) & 1;
    const int ct   = tid >> 7;                           // col tile 0..7
    const int col  = ct * 16 + (lane & 15);
    const int kb   = ks * 32 + 8 * (lane >> 4);

    v8s f;
#pragma unroll
    for (int j = 0; j < 8; ++j) {
        const int k = kb + j;
        const float v = (col < 64)
            ? (w[col * 128 + k] - w[col * 128 + 64 + k])
            : w[(col - 64) * 128 + 64 + k];
        f[j] = (short)f2bf(v);
    }
    wfrag[tid] = f;
}

// ---------------------------------------------------------------------------
// Kernel 1: projection GEMM via MFMA.  [32768x64] x [64x128] -> cbuf|nbuf.
// Block 256 = 4 waves, 64 rows/block, wave = 16 rows x 128 cols
// = 8 col-tiles x 2 K-steps of v_mfma_f32_16x16x32_bf16.
// A-frag: row = lane&15, k = ks*32 + 8*(lane>>4)+j (two float4 loads + RNE).
// B-frags: 16 coalesced dwordx4 from wfrag (L2-hot, 16KB total).
// C/D: col = lane&15, row = (lane>>4)*4 + reg.  bias folded into acc init.
// ---------------------------------------------------------------------------
__global__ __launch_bounds__(256) void proj_mfma(
    const float* __restrict__ x,
    const v8s*  __restrict__ wfrag,
    const float* __restrict__ bias,
    float* __restrict__ cbuf,
    unsigned short* __restrict__ nbuf)
{
    const int lane  = threadIdx.x & 63;
    const int wv    = threadIdx.x >> 6;
    const int batch = blockIdx.x & 7;                    // XCD-affine
    const int chunk = blockIdx.x >> 3;                   // 0..63
    const int r0    = batch * N_PTS + chunk * 64 + wv * 16;

    // B fragments (whole 64x128 weight matrix)
    v8s bfrag[8][2];
#pragma unroll
    for (int ct = 0; ct < 8; ++ct)
#pragma unroll
        for (int ks = 0; ks < 2; ++ks)
            bfrag[ct][ks] = wfrag[(ct * 2 + ks) * 64 + lane];

    // A fragments for this wave's 16 rows
    const int arow = r0 + (lane & 15);
    const int koff = 8 * (lane >> 4);
    v8s afrag[2];
#pragma unroll
    for (int ks = 0; ks < 2; ++ks) {
        const float* xp = x + (size_t)arow * C_IN + ks * 32 + koff;
        const float4 q0 = *(const float4*)xp;
        const float4 q1 = *(const float4*)(xp + 4);
        v8s a;
        a[0] = (short)f2bf(q0.x); a[1] = (short)f2bf(q0.y);
        a[2] = (short)f2bf(q0.z); a[3] = (short)f2bf(q0.w);
        a[4] = (short)f2bf(q1.x); a[5] = (short)f2bf(q1.y);
        a[6] = (short)f2bf(q1.z); a[7] = (short)f2bf(q1.w);
        afrag[ks] = a;
    }

    v4f acc[8];
#pragma unroll
    for (int ct = 0; ct < 4; ++ct) {                     // cbuf: bias init
        const float bv = bias[ct * 16 + (lane & 15)];
        acc[ct] = (v4f){bv, bv, bv, bv};
    }
#pragma unroll
    for (int ct = 4; ct < 8; ++ct)                       // nbuf: zero init
        acc[ct] = (v4f){0.f, 0.f, 0.f, 0.f};

#pragma unroll
    for (int ks = 0; ks < 2; ++ks)
#pragma unroll
        for (int ct = 0; ct < 8; ++ct)
            acc[ct] = __builtin_amdgcn_mfma_f32_16x16x32_bf16(
                afrag[ks], bfrag[ct][ks], acc[ct], 0, 0, 0);

    // store: row = r0 + (lane>>4)*4 + reg, col = ct*16 + (lane&15)
    const int crow0 = r0 + (lane >> 4) * 4;
    const int ccol  = lane & 15;
#pragma unroll
    for (int ct = 0; ct < 4; ++ct)
#pragma unroll
        for (int reg = 0; reg < 4; ++reg)
            cbuf[(size_t)(crow0 + reg) * C_OUT + ct * 16 + ccol] = acc[ct][reg];
#pragma unroll
    for (int ct = 4; ct < 8; ++ct)
#pragma unroll
        for (int reg = 0; reg < 4; ++reg)
            nbuf[(size_t)(crow0 + reg) * C_OUT + (ct - 4) * 16 + ccol] =
                f2bf(acc[ct][reg]);
}

// ---------------------------------------------------------------------------
// Kernel 2: gather + max + relu + transposed store (unchanged).
//   out[b][o][n] = relu( cbuf[b,n][o] + max_k nbuf[b, idx[b,n,k]][o] )
// ---------------------------------------------------------------------------
__global__ __launch_bounds__(256) void gather_max_kernel(
    const float* __restrict__ cbuf,
    const unsigned short* __restrict__ nbuf,
    const int* __restrict__ eidx,
    float* __restrict__ out)
{
    __shared__ float tile[64][65];

    const int t    = threadIdx.x;
    const int lane = t & 63;
    const int g    = t >> 6;                // wave 0..3
    const int b    = blockIdx.x & 7;        // batch == XCD
    const int tn   = blockIdx.x >> 3;       // 0..63
    const int n0   = tn * 64;

    const unsigned short* nb = nbuf + (size_t)b * N_PTS * C_OUT;
    const int o4  = (lane & 15) * 4;        // first of 4 channels
    const int sub = lane >> 4;              // row within quad

    for (int i = 0; i < 4; ++i) {
        const int rbase = b * N_PTS + n0 + g * 16 + i * 4;
        int myidx = eidx[(size_t)rbase * KNN + lane] & (N_PTS - 1);

        const int r = rbase + sub;
        const float4 cv = *(const float4*)(cbuf + (size_t)r * C_OUT + o4);

        float m0 = -1e30f, m1 = -1e30f, m2 = -1e30f, m3 = -1e30f;
#pragma unroll
        for (int k = 0; k < KNN; ++k) {
            const int idx = __shfl(myidx, (lane & 48) | k);
            const uint2 v = *(const uint2*)(nb + (size_t)idx * C_OUT + o4);
            m0 = fmaxf(m0, __uint_as_float(v.x << 16));
            m1 = fmaxf(m1, __uint_as_float(v.x & 0xffff0000u));
            m2 = fmaxf(m2, __uint_as_float(v.y << 16));
            m3 = fmaxf(m3, __uint_as_float(v.y & 0xffff0000u));
        }

        const int nl = g * 16 + i * 4 + sub;
        tile[nl][o4 + 0] = fmaxf(cv.x + m0, 0.f);   // relu(max)==max(relu)
        tile[nl][o4 + 1] = fmaxf(cv.y + m1, 0.f);
        tile[nl][o4 + 2] = fmaxf(cv.z + m2, 0.f);
        tile[nl][o4 + 3] = fmaxf(cv.w + m3, 0.f);
    }

    __syncthreads();

    float* ob = out + (size_t)b * C_OUT * N_PTS + n0;
#pragma unroll
    for (int j = 0; j < 16; ++j) {
        const int o = g * 16 + j;
        ob[(size_t)o * N_PTS + lane] = tile[lane][o];
    }
}

// ---------------------------------------------------------------------------
extern "C" void kernel_launch(void* const* d_in, const int* in_sizes, int n_in,
                              void* d_out, int out_size, void* d_ws, size_t ws_size,
                              hipStream_t stream)
{
    const float* x    = (const float*)d_in[0];
    const int*   eidx = (const int*)d_in[1];    // int64 in ref -> int32 here
    const float* w    = (const float*)d_in[2];  // (64, 128)
    const float* bias = (const float*)d_in[3];  // (64,)
    float*       out  = (float*)d_out;          // (8, 64, 64, 64) f32

    float*          cbuf = (float*)d_ws;                                 // 8 MiB
    unsigned short* nbuf = (unsigned short*)(cbuf + (size_t)ROWS * C_OUT); // 4 MiB
    v8s*            wfrag = (v8s*)((char*)nbuf + (size_t)ROWS * C_OUT * 2); // 16 KiB

    wprep_kernel<<<4, 256, 0, stream>>>(w, wfrag);
    proj_mfma<<<ROWS / 64, 256, 0, stream>>>(x, wfrag, bias, cbuf, nbuf);
    gather_max_kernel<<<B_SZ * (N_PTS / 64), 256, 0, stream>>>(cbuf, nbuf, eidx, out);
}

// Round 9
// 28.883 us; speedup vs baseline: 1.9433x; 1.0135x over previous
//
#include <hip/hip_runtime.h>
#include <hip/hip_bf16.h>
#include <stdint.h>

#define B_SZ    8
#define N_PTS   4096
#define C_IN    64
#define C_OUT   64
#define KNN     16
#define ROWS    (B_SZ * N_PTS)      // 32768

typedef __attribute__((ext_vector_type(8))) short v8s;   // 8 bf16 (4 VGPR)
typedef __attribute__((ext_vector_type(4))) float v4f;   // MFMA acc

__device__ inline unsigned short f2bf(float f) {         // RNE f32->bf16
    unsigned int u = __float_as_uint(f);
    return (unsigned short)((u + 0x7FFFu + ((u >> 16) & 1u)) >> 16);
}

// ---------------------------------------------------------------------------
// Kernel 0: pack combined weights B[k][col] (64x128) into MFMA B-fragment
// order: frag (ct,ks,lane) holds cols ct*16+(lane&15), k = ks*32+8*(lane>>4)+j.
//   col <  64: B[k][col] = W1[col][k] - W2[col][k]
//   col >= 64: B[k][col] = W2[col-64][k]
// ---------------------------------------------------------------------------
__global__ void wprep_kernel(const float* __restrict__ w, v8s* __restrict__ wfrag)
{
    const int tid = blockIdx.x * 256 + threadIdx.x;      // 0..1023
    if (tid >= 1024) return;
    const int lane = tid & 63;
    const int ks   = (tid >> 6) & 1;
    const int ct   = tid >> 7;                           // col tile 0..7
    const int col  = ct * 16 + (lane & 15);
    const int kb   = ks * 32 + 8 * (lane >> 4);

    v8s f;
#pragma unroll
    for (int j = 0; j < 8; ++j) {
        const int k = kb + j;
        const float v = (col < 64)
            ? (w[col * 128 + k] - w[col * 128 + 64 + k])
            : w[(col - 64) * 128 + 64 + k];
        f[j] = (short)f2bf(v);
    }
    wfrag[tid] = f;
}

// ---------------------------------------------------------------------------
// Kernel 1: projection GEMM via MFMA — LOW-REGISTER variant.
// Block 256 = 4 waves, 32 rows/block.  Wave wv:
//   rq = wv&1  -> rows rq*16..rq*16+15
//   h  = wv>>1 -> h=0: cbuf cols 0..63 (bias init), h=1: nbuf cols (bf16)
// Per-wave state: bfrag[4][2]=32 VGPR, acc[4]=16, afrag[2]=8  (~80 total,
// no spill; round-8's 16-frag variant likely clamped to 128 and spilled).
// A-frag: row = lane&15, k = ks*32 + 8*(lane>>4)+j.
// C/D: col = ct*16 + (lane&15), row = (lane>>4)*4 + reg.
// ---------------------------------------------------------------------------
__global__ __launch_bounds__(256, 2) void proj_mfma(
    const float* __restrict__ x,
    const v8s*  __restrict__ wfrag,
    const float* __restrict__ bias,
    float* __restrict__ cbuf,
    unsigned short* __restrict__ nbuf)
{
    const int lane  = threadIdx.x & 63;
    const int wv    = threadIdx.x >> 6;
    const int rq    = wv & 1;                            // row quarter
    const int h     = wv >> 1;                           // 0: cbuf, 1: nbuf
    const int batch = blockIdx.x & 7;                    // XCD-affine
    const int chunk = blockIdx.x >> 3;                   // 0..127
    const int r0    = batch * N_PTS + chunk * 32 + rq * 16;

    // B fragments for this half (4 col-tiles x 2 K-steps)
    v8s bfrag[4][2];
#pragma unroll
    for (int ct = 0; ct < 4; ++ct)
#pragma unroll
        for (int ks = 0; ks < 2; ++ks)
            bfrag[ct][ks] = wfrag[((h * 4 + ct) * 2 + ks) * 64 + lane];

    // A fragments for this wave's 16 rows
    const int arow = r0 + (lane & 15);
    const int koff = 8 * (lane >> 4);
    v8s afrag[2];
#pragma unroll
    for (int ks = 0; ks < 2; ++ks) {
        const float* xp = x + (size_t)arow * C_IN + ks * 32 + koff;
        const float4 q0 = *(const float4*)xp;
        const float4 q1 = *(const float4*)(xp + 4);
        v8s a;
        a[0] = (short)f2bf(q0.x); a[1] = (short)f2bf(q0.y);
        a[2] = (short)f2bf(q0.z); a[3] = (short)f2bf(q0.w);
        a[4] = (short)f2bf(q1.x); a[5] = (short)f2bf(q1.y);
        a[6] = (short)f2bf(q1.z); a[7] = (short)f2bf(q1.w);
        afrag[ks] = a;
    }

    v4f acc[4];
    if (h == 0) {
#pragma unroll
        for (int ct = 0; ct < 4; ++ct) {
            const float bv = bias[ct * 16 + (lane & 15)];
            acc[ct] = (v4f){bv, bv, bv, bv};
        }
    } else {
#pragma unroll
        for (int ct = 0; ct < 4; ++ct)
            acc[ct] = (v4f){0.f, 0.f, 0.f, 0.f};
    }

#pragma unroll
    for (int ks = 0; ks < 2; ++ks)
#pragma unroll
        for (int ct = 0; ct < 4; ++ct)
            acc[ct] = __builtin_amdgcn_mfma_f32_16x16x32_bf16(
                afrag[ks], bfrag[ct][ks], acc[ct], 0, 0, 0);

    // store: row = r0 + (lane>>4)*4 + reg, col = ct*16 + (lane&15)
    const int crow0 = r0 + (lane >> 4) * 4;
    const int ccol  = lane & 15;
    if (h == 0) {
#pragma unroll
        for (int ct = 0; ct < 4; ++ct)
#pragma unroll
            for (int reg = 0; reg < 4; ++reg)
                cbuf[(size_t)(crow0 + reg) * C_OUT + ct * 16 + ccol] = acc[ct][reg];
    } else {
#pragma unroll
        for (int ct = 0; ct < 4; ++ct)
#pragma unroll
            for (int reg = 0; reg < 4; ++reg)
                nbuf[(size_t)(crow0 + reg) * C_OUT + ct * 16 + ccol] =
                    f2bf(acc[ct][reg]);
    }
}

// ---------------------------------------------------------------------------
// Kernel 2: gather + max + relu + transposed store (unchanged).
//   out[b][o][n] = relu( cbuf[b,n][o] + max_k nbuf[b, idx[b,n,k]][o] )
// ---------------------------------------------------------------------------
__global__ __launch_bounds__(256) void gather_max_kernel(
    const float* __restrict__ cbuf,
    const unsigned short* __restrict__ nbuf,
    const int* __restrict__ eidx,
    float* __restrict__ out)
{
    __shared__ float tile[64][65];

    const int t    = threadIdx.x;
    const int lane = t & 63;
    const int g    = t >> 6;                // wave 0..3
    const int b    = blockIdx.x & 7;        // batch == XCD
    const int tn   = blockIdx.x >> 3;       // 0..63
    const int n0   = tn * 64;

    const unsigned short* nb = nbuf + (size_t)b * N_PTS * C_OUT;
    const int o4  = (lane & 15) * 4;        // first of 4 channels
    const int sub = lane >> 4;              // row within quad

    for (int i = 0; i < 4; ++i) {
        const int rbase = b * N_PTS + n0 + g * 16 + i * 4;
        int myidx = eidx[(size_t)rbase * KNN + lane] & (N_PTS - 1);

        const int r = rbase + sub;
        const float4 cv = *(const float4*)(cbuf + (size_t)r * C_OUT + o4);

        float m0 = -1e30f, m1 = -1e30f, m2 = -1e30f, m3 = -1e30f;
#pragma unroll
        for (int k = 0; k < KNN; ++k) {
            const int idx = __shfl(myidx, (lane & 48) | k);
            const uint2 v = *(const uint2*)(nb + (size_t)idx * C_OUT + o4);
            m0 = fmaxf(m0, __uint_as_float(v.x << 16));
            m1 = fmaxf(m1, __uint_as_float(v.x & 0xffff0000u));
            m2 = fmaxf(m2, __uint_as_float(v.y << 16));
            m3 = fmaxf(m3, __uint_as_float(v.y & 0xffff0000u));
        }

        const int nl = g * 16 + i * 4 + sub;
        tile[nl][o4 + 0] = fmaxf(cv.x + m0, 0.f);   // relu(max)==max(relu)
        tile[nl][o4 + 1] = fmaxf(cv.y + m1, 0.f);
        tile[nl][o4 + 2] = fmaxf(cv.z + m2, 0.f);
        tile[nl][o4 + 3] = fmaxf(cv.w + m3, 0.f);
    }

    __syncthreads();

    float* ob = out + (size_t)b * C_OUT * N_PTS + n0;
#pragma unroll
    for (int j = 0; j < 16; ++j) {
        const int o = g * 16 + j;
        ob[(size_t)o * N_PTS + lane] = tile[lane][o];
    }
}

// ---------------------------------------------------------------------------
extern "C" void kernel_launch(void* const* d_in, const int* in_sizes, int n_in,
                              void* d_out, int out_size, void* d_ws, size_t ws_size,
                              hipStream_t stream)
{
    const float* x    = (const float*)d_in[0];
    const int*   eidx = (const int*)d_in[1];    // int64 in ref -> int32 here
    const float* w    = (const float*)d_in[2];  // (64, 128)
    const float* bias = (const float*)d_in[3];  // (64,)
    float*       out  = (float*)d_out;          // (8, 64, 64, 64) f32

    float*          cbuf = (float*)d_ws;                                   // 8 MiB
    unsigned short* nbuf = (unsigned short*)(cbuf + (size_t)ROWS * C_OUT); // 4 MiB
    v8s*            wfrag = (v8s*)((char*)nbuf + (size_t)ROWS * C_OUT * 2); // 16 KiB

    wprep_kernel<<<4, 256, 0, stream>>>(w, wfrag);
    proj_mfma<<<ROWS / 32, 256, 0, stream>>>(x, wfrag, bias, cbuf, nbuf);
    gather_max_kernel<<<B_SZ * (N_PTS / 64), 256, 0, stream>>>(cbuf, nbuf, eidx, out);
}

// Round 10
// 23.224 us; speedup vs baseline: 2.4169x; 1.2437x over previous
//
#include <hip/hip_runtime.h>
#include <hip/hip_bf16.h>
#include <stdint.h>

#define B_SZ    8
#define N_PTS   4096
#define C_IN    64
#define C_OUT   64
#define KNN     16
#define ROWS    (B_SZ * N_PTS)      // 32768

typedef __attribute__((ext_vector_type(8))) short v8s;   // 8 bf16 (4 VGPR)
typedef __attribute__((ext_vector_type(4))) float v4f;   // MFMA acc

__device__ inline unsigned short f2bf(float f) {         // RNE f32->bf16
    unsigned int u = __float_as_uint(f);
    return (unsigned short)((u + 0x7FFFu + ((u >> 16) & 1u)) >> 16);
}

// ---------------------------------------------------------------------------
// Kernel 0: pack combined weights B[k][col] (64x128) into MFMA B-fragment
// order. LDS-STAGED: each block copies all of w (32 KB) into LDS with 8
// coalesced float4 rounds (round-8/9 version did 8192 scattered 4B HBM loads
// on 4 CUs -> latency-bound ~5-10us). Frag built from LDS, written coalesced.
//   col <  64: B[k][col] = W1[col][k] - W2[col][k]
//   col >= 64: B[k][col] = W2[col-64][k]
// ---------------------------------------------------------------------------
__global__ __launch_bounds__(256) void wprep_kernel(const float* __restrict__ w,
                                                    v8s* __restrict__ wfrag)
{
    __shared__ float wl[2 * C_IN * C_OUT];   // 8192 floats = 32 KiB
    const int t = threadIdx.x;
    {
        const float4* src = (const float4*)w;
        float4*       dst = (float4*)wl;
#pragma unroll
        for (int i = 0; i < 8; ++i)          // coalesced: 4 KB per round
            dst[i * 256 + t] = src[i * 256 + t];
    }
    __syncthreads();

    const int tid  = blockIdx.x * 256 + t;   // 0..1023 (grid = 4 blocks)
    const int lane = tid & 63;
    const int ks   = (tid >> 6) & 1;
    const int ct   = tid >> 7;               // col tile 0..7
    const int col  = ct * 16 + (lane & 15);
    const int kb   = ks * 32 + 8 * (lane >> 4);

    v8s f;
#pragma unroll
    for (int j = 0; j < 8; ++j) {
        const int k = kb + j;
        const float v = (col < 64)
            ? (wl[col * 128 + k] - wl[col * 128 + 64 + k])
            : wl[(col - 64) * 128 + 64 + k];
        f[j] = (short)f2bf(v);
    }
    wfrag[tid] = f;                          // coalesced 16B/lane
}

// ---------------------------------------------------------------------------
// Kernel 1: projection GEMM via MFMA (byte-identical to round 9).
// Block 256 = 4 waves, 32 rows/block.  Wave wv:
//   rq = wv&1  -> rows rq*16..rq*16+15
//   h  = wv>>1 -> h=0: cbuf cols 0..63 (bias init), h=1: nbuf cols (bf16)
// ---------------------------------------------------------------------------
__global__ __launch_bounds__(256, 2) void proj_mfma(
    const float* __restrict__ x,
    const v8s*  __restrict__ wfrag,
    const float* __restrict__ bias,
    float* __restrict__ cbuf,
    unsigned short* __restrict__ nbuf)
{
    const int lane  = threadIdx.x & 63;
    const int wv    = threadIdx.x >> 6;
    const int rq    = wv & 1;                            // row quarter
    const int h     = wv >> 1;                           // 0: cbuf, 1: nbuf
    const int batch = blockIdx.x & 7;                    // XCD-affine
    const int chunk = blockIdx.x >> 3;                   // 0..127
    const int r0    = batch * N_PTS + chunk * 32 + rq * 16;

    v8s bfrag[4][2];
#pragma unroll
    for (int ct = 0; ct < 4; ++ct)
#pragma unroll
        for (int ks = 0; ks < 2; ++ks)
            bfrag[ct][ks] = wfrag[((h * 4 + ct) * 2 + ks) * 64 + lane];

    const int arow = r0 + (lane & 15);
    const int koff = 8 * (lane >> 4);
    v8s afrag[2];
#pragma unroll
    for (int ks = 0; ks < 2; ++ks) {
        const float* xp = x + (size_t)arow * C_IN + ks * 32 + koff;
        const float4 q0 = *(const float4*)xp;
        const float4 q1 = *(const float4*)(xp + 4);
        v8s a;
        a[0] = (short)f2bf(q0.x); a[1] = (short)f2bf(q0.y);
        a[2] = (short)f2bf(q0.z); a[3] = (short)f2bf(q0.w);
        a[4] = (short)f2bf(q1.x); a[5] = (short)f2bf(q1.y);
        a[6] = (short)f2bf(q1.z); a[7] = (short)f2bf(q1.w);
        afrag[ks] = a;
    }

    v4f acc[4];
    if (h == 0) {
#pragma unroll
        for (int ct = 0; ct < 4; ++ct) {
            const float bv = bias[ct * 16 + (lane & 15)];
            acc[ct] = (v4f){bv, bv, bv, bv};
        }
    } else {
#pragma unroll
        for (int ct = 0; ct < 4; ++ct)
            acc[ct] = (v4f){0.f, 0.f, 0.f, 0.f};
    }

#pragma unroll
    for (int ks = 0; ks < 2; ++ks)
#pragma unroll
        for (int ct = 0; ct < 4; ++ct)
            acc[ct] = __builtin_amdgcn_mfma_f32_16x16x32_bf16(
                afrag[ks], bfrag[ct][ks], acc[ct], 0, 0, 0);

    const int crow0 = r0 + (lane >> 4) * 4;
    const int ccol  = lane & 15;
    if (h == 0) {
#pragma unroll
        for (int ct = 0; ct < 4; ++ct)
#pragma unroll
            for (int reg = 0; reg < 4; ++reg)
                cbuf[(size_t)(crow0 + reg) * C_OUT + ct * 16 + ccol] = acc[ct][reg];
    } else {
#pragma unroll
        for (int ct = 0; ct < 4; ++ct)
#pragma unroll
            for (int reg = 0; reg < 4; ++reg)
                nbuf[(size_t)(crow0 + reg) * C_OUT + ct * 16 + ccol] =
                    f2bf(acc[ct][reg]);
    }
}

// ---------------------------------------------------------------------------
// Kernel 2: gather + max + relu + transposed store — OCCUPANCY version.
// 32-row tiles -> 1024 blocks = 4 blocks/CU = 16 waves/CU (was 2 blk/CU):
// more in-flight L2 gathers to hide ~200cyc latency.
//   out[b][o][n] = relu( cbuf[b,n][o] + max_k nbuf[b, idx[b,n,k]][o] )
// ---------------------------------------------------------------------------
__global__ __launch_bounds__(256) void gather_max_kernel(
    const float* __restrict__ cbuf,
    const unsigned short* __restrict__ nbuf,
    const int* __restrict__ eidx,
    float* __restrict__ out)
{
    __shared__ float tile[32][65];

    const int t    = threadIdx.x;
    const int lane = t & 63;
    const int g    = t >> 6;                // wave 0..3
    const int b    = blockIdx.x & 7;        // batch == XCD
    const int tn   = blockIdx.x >> 3;       // 0..127
    const int n0   = tn * 32;

    const unsigned short* nb = nbuf + (size_t)b * N_PTS * C_OUT;
    const int o4  = (lane & 15) * 4;        // first of 4 channels
    const int sub = lane >> 4;              // row within quad

#pragma unroll
    for (int i = 0; i < 2; ++i) {
        const int rbase = b * N_PTS + n0 + g * 8 + i * 4;
        int myidx = eidx[(size_t)rbase * KNN + lane] & (N_PTS - 1);

        const int r = rbase + sub;
        const float4 cv = *(const float4*)(cbuf + (size_t)r * C_OUT + o4);

        float m0 = -1e30f, m1 = -1e30f, m2 = -1e30f, m3 = -1e30f;
#pragma unroll
        for (int k = 0; k < KNN; ++k) {
            const int idx = __shfl(myidx, (lane & 48) | k);
            const uint2 v = *(const uint2*)(nb + (size_t)idx * C_OUT + o4);
            m0 = fmaxf(m0, __uint_as_float(v.x << 16));
            m1 = fmaxf(m1, __uint_as_float(v.x & 0xffff0000u));
            m2 = fmaxf(m2, __uint_as_float(v.y << 16));
            m3 = fmaxf(m3, __uint_as_float(v.y & 0xffff0000u));
        }

        const int nl = g * 8 + i * 4 + sub;
        tile[nl][o4 + 0] = fmaxf(cv.x + m0, 0.f);   // relu(max)==max(relu)
        tile[nl][o4 + 1] = fmaxf(cv.y + m1, 0.f);
        tile[nl][o4 + 2] = fmaxf(cv.z + m2, 0.f);
        tile[nl][o4 + 3] = fmaxf(cv.w + m3, 0.f);
    }

    __syncthreads();

    // out[b][o][n0+nn]: lanes 0-31 cover o=even slot, 32-63 the next o.
    float* ob = out + (size_t)b * C_OUT * N_PTS + n0;
    const int nn = lane & 31;
    const int oh = lane >> 5;
#pragma unroll
    for (int j = 0; j < 8; ++j) {
        const int o = g * 16 + j * 2 + oh;
        ob[(size_t)o * N_PTS + nn] = tile[nn][o];   // 2x128B segments
    }
}

// ---------------------------------------------------------------------------
extern "C" void kernel_launch(void* const* d_in, const int* in_sizes, int n_in,
                              void* d_out, int out_size, void* d_ws, size_t ws_size,
                              hipStream_t stream)
{
    const float* x    = (const float*)d_in[0];
    const int*   eidx = (const int*)d_in[1];    // int64 in ref -> int32 here
    const float* w    = (const float*)d_in[2];  // (64, 128)
    const float* bias = (const float*)d_in[3];  // (64,)
    float*       out  = (float*)d_out;          // (8, 64, 64, 64) f32

    float*          cbuf = (float*)d_ws;                                   // 8 MiB
    unsigned short* nbuf = (unsigned short*)(cbuf + (size_t)ROWS * C_OUT); // 4 MiB
    v8s*            wfrag = (v8s*)((char*)nbuf + (size_t)ROWS * C_OUT * 2); // 16 KiB

    wprep_kernel<<<4, 256, 0, stream>>>(w, wfrag);
    proj_mfma<<<ROWS / 32, 256, 0, stream>>>(x, wfrag, bias, cbuf, nbuf);
    gather_max_kernel<<<B_SZ * (N_PTS / 32), 256, 0, stream>>>(cbuf, nbuf, eidx, out);
}

// Round 12
// 20.758 us; speedup vs baseline: 2.7040x; 1.1188x over previous
//
#include <hip/hip_runtime.h>
#include <stdint.h>

#define B_SZ    8
#define N_PTS   4096
#define C_IN    64
#define C_OUT   64
#define KNN     16
#define ROWS    (B_SZ * N_PTS)      // 32768

typedef __attribute__((ext_vector_type(8))) short v8s;   // 8 bf16 (4 VGPR)
typedef __attribute__((ext_vector_type(4))) float v4f;   // MFMA acc

__device__ inline unsigned short f2bf(float f) {         // RNE f32->bf16
    unsigned int u = __float_as_uint(f);
    return (unsigned short)((u + 0x7FFFu + ((u >> 16) & 1u)) >> 16);
}

// ---------------------------------------------------------------------------
// Kernel 0: pack combined weights B[k][col] (64x128) into MFMA B-fragment
// order (LDS-staged, coalesced).  frag tid = ct*128 + ks*64 + lane holds
// cols ct*16+(lane&15), k = ks*32 + 8*(lane>>4) + j.
//   col <  64: B[k][col] = W1[col][k] - W2[col][k]   (cbuf weights)
//   col >= 64: B[k][col] = W2[col-64][k]             (nbuf weights)
// ---------------------------------------------------------------------------
__global__ __launch_bounds__(256) void wprep_kernel(const float* __restrict__ w,
                                                    v8s* __restrict__ wfrag)
{
    __shared__ float wl[2 * C_IN * C_OUT];   // 32 KiB
    const int t = threadIdx.x;
    {
        const float4* src = (const float4*)w;
        float4*       dst = (float4*)wl;
#pragma unroll
        for (int i = 0; i < 8; ++i)
            dst[i * 256 + t] = src[i * 256 + t];
    }
    __syncthreads();

    const int tid  = blockIdx.x * 256 + t;   // 0..1023 (grid = 4)
    const int lane = tid & 63;
    const int ks   = (tid >> 6) & 1;
    const int ct   = tid >> 7;
    const int col  = ct * 16 + (lane & 15);
    const int kb   = ks * 32 + 8 * (lane >> 4);

    v8s f;
#pragma unroll
    for (int j = 0; j < 8; ++j) {
        const int k = kb + j;
        const float v = (col < 64)
            ? (wl[col * 128 + k] - wl[col * 128 + 64 + k])
            : wl[(col - 64) * 128 + 64 + k];
        f[j] = (short)f2bf(v);
    }
    wfrag[tid] = f;
}

// ---------------------------------------------------------------------------
// Kernel 1: nbuf-only projection (MFMA).  nbuf[r][o] = x[r]·W2[o]  (bf16)
// 64 rows/block, 4 waves; wave wv handles rows wv*16..wv*16+15, all 64 cols.
// bfrag = W2 frags (ct 4..7).  A-frag from global x (float4 + RNE pack).
// ---------------------------------------------------------------------------
__global__ __launch_bounds__(256, 2) void proj_nbuf(
    const float* __restrict__ x,
    const v8s*  __restrict__ wfrag,
    unsigned short* __restrict__ nbuf)
{
    const int lane  = threadIdx.x & 63;
    const int wv    = threadIdx.x >> 6;
    const int batch = blockIdx.x & 7;                    // XCD-affine
    const int chunk = blockIdx.x >> 3;                   // 0..63
    const int r0    = batch * N_PTS + chunk * 64 + wv * 16;

    v8s bfrag[4][2];
#pragma unroll
    for (int ct = 0; ct < 4; ++ct)
#pragma unroll
        for (int ks = 0; ks < 2; ++ks)
            bfrag[ct][ks] = wfrag[((4 + ct) * 2 + ks) * 64 + lane];

    const int arow = r0 + (lane & 15);
    const int koff = 8 * (lane >> 4);
    v8s afrag[2];
#pragma unroll
    for (int ks = 0; ks < 2; ++ks) {
        const float* xp = x + (size_t)arow * C_IN + ks * 32 + koff;
        const float4 q0 = *(const float4*)xp;
        const float4 q1 = *(const float4*)(xp + 4);
        v8s a;
        a[0] = (short)f2bf(q0.x); a[1] = (short)f2bf(q0.y);
        a[2] = (short)f2bf(q0.z); a[3] = (short)f2bf(q0.w);
        a[4] = (short)f2bf(q1.x); a[5] = (short)f2bf(q1.y);
        a[6] = (short)f2bf(q1.z); a[7] = (short)f2bf(q1.w);
        afrag[ks] = a;
    }

    v4f acc[4];
#pragma unroll
    for (int ct = 0; ct < 4; ++ct)
        acc[ct] = (v4f){0.f, 0.f, 0.f, 0.f};

#pragma unroll
    for (int ks = 0; ks < 2; ++ks)
#pragma unroll
        for (int ct = 0; ct < 4; ++ct)
            acc[ct] = __builtin_amdgcn_mfma_f32_16x16x32_bf16(
                afrag[ks], bfrag[ct][ks], acc[ct], 0, 0, 0);

    const int crow0 = r0 + (lane >> 4) * 4;
    const int ccol  = lane & 15;
#pragma unroll
    for (int ct = 0; ct < 4; ++ct)
#pragma unroll
        for (int reg = 0; reg < 4; ++reg)
            nbuf[(size_t)(crow0 + reg) * C_OUT + ct * 16 + ccol] =
                f2bf(acc[ct][reg]);
}

// ---------------------------------------------------------------------------
// Kernel 2: fused cbuf(MFMA, LDS-only) + gather + max + relu + store.
// Block (b,tn) owns 32 rows. Phase A: stage x tile. Phase B: recompute the
// cbuf tile into LDS (cbuf never touches global — saves 16 MB HBM round-trip).
// Phase C: gather nbuf (L2-local via XCD affinity), add cv, max, relu,
// transposed coalesced store.
// ---------------------------------------------------------------------------
#define PITCH 68

__global__ __launch_bounds__(256) void gather_fused(
    const float* __restrict__ x,
    const v8s*  __restrict__ wfrag,
    const float* __restrict__ bias,
    const int* __restrict__ eidx,
    const unsigned short* __restrict__ nbuf,
    float* __restrict__ out)
{
    __shared__ float sm[32][PITCH];         // 8.5 KiB, reused x->cbuf->result

    const int t    = threadIdx.x;
    const int lane = t & 63;
    const int wv   = t >> 6;                // wave 0..3
    const int b    = blockIdx.x & 7;        // batch == XCD
    const int tn   = blockIdx.x >> 3;       // 0..127
    const int n0   = tn * 32;
    const int r0g  = b * N_PTS + n0;

    // ---- Phase A: stage 32 x-rows (8 KB) coalesced ----
    {
        const float4* xsrc = (const float4*)(x + (size_t)r0g * C_IN);
#pragma unroll
        for (int i = 0; i < 2; ++i) {
            const int idx = i * 256 + t;    // 0..511
            *(float4*)&sm[idx >> 4][(idx & 15) * 4] = xsrc[idx];
        }
    }
    __syncthreads();

    // ---- Phase B: cbuf tile via MFMA (wave = row-half x col-half) ----
    const int rq  = wv & 1;                 // rows rq*16..+15
    const int ch  = wv >> 1;                // cols ch*32..+31
    const int rl0 = rq * 16;

    v8s bfrag[2][2];
#pragma unroll
    for (int ct = 0; ct < 2; ++ct)
#pragma unroll
        for (int ks = 0; ks < 2; ++ks)
            bfrag[ct][ks] = wfrag[((ch * 2 + ct) * 2 + ks) * 64 + lane];

    const int rl   = rl0 + (lane & 15);
    const int koff = 8 * (lane >> 4);
    v8s afrag[2];
#pragma unroll
    for (int ks = 0; ks < 2; ++ks) {
        const float* xp = &sm[rl][ks * 32 + koff];
        const float4 q0 = *(const float4*)xp;
        const float4 q1 = *(const float4*)(xp + 4);
        v8s a;
        a[0] = (short)f2bf(q0.x); a[1] = (short)f2bf(q0.y);
        a[2] = (short)f2bf(q0.z); a[3] = (short)f2bf(q0.w);
        a[4] = (short)f2bf(q1.x); a[5] = (short)f2bf(q1.y);
        a[6] = (short)f2bf(q1.z); a[7] = (short)f2bf(q1.w);
        afrag[ks] = a;
    }

    v4f acc[2];
#pragma unroll
    for (int ct = 0; ct < 2; ++ct) {
        const float bv = bias[ch * 32 + ct * 16 + (lane & 15)];
        acc[ct] = (v4f){bv, bv, bv, bv};
    }
#pragma unroll
    for (int ks = 0; ks < 2; ++ks)
#pragma unroll
        for (int ct = 0; ct < 2; ++ct)
            acc[ct] = __builtin_amdgcn_mfma_f32_16x16x32_bf16(
                afrag[ks], bfrag[ct][ks], acc[ct], 0, 0, 0);

    __syncthreads();                        // all afrag reads done

    const int orow = rl0 + (lane >> 4) * 4;
    const int ccol = lane & 15;
#pragma unroll
    for (int ct = 0; ct < 2; ++ct)
#pragma unroll
        for (int reg = 0; reg < 4; ++reg)
            sm[orow + reg][ch * 32 + ct * 16 + ccol] = acc[ct][reg];

    __syncthreads();

    // ---- Phase C: gather + max + relu ----
    const unsigned short* nb = nbuf + (size_t)b * N_PTS * C_OUT;
    const int o4  = (lane & 15) * 4;
    const int sub = lane >> 4;

#pragma unroll
    for (int i = 0; i < 2; ++i) {
        const int rbl   = wv * 8 + i * 4;   // local row base
        const int rbase = r0g + rbl;
        int myidx = eidx[(size_t)rbase * KNN + lane] & (N_PTS - 1);

        const float4 cv = *(const float4*)&sm[rbl + sub][o4];

        float m0 = -1e30f, m1 = -1e30f, m2 = -1e30f, m3 = -1e30f;
#pragma unroll
        for (int k = 0; k < KNN; ++k) {
            const int idx = __shfl(myidx, (lane & 48) | k);
            const uint2 v = *(const uint2*)(nb + (size_t)idx * C_OUT + o4);
            m0 = fmaxf(m0, __uint_as_float(v.x << 16));
            m1 = fmaxf(m1, __uint_as_float(v.x & 0xffff0000u));
            m2 = fmaxf(m2, __uint_as_float(v.y << 16));
            m3 = fmaxf(m3, __uint_as_float(v.y & 0xffff0000u));
        }

        const int nl = rbl + sub;           // each (row,col4) owned by 1 lane
        sm[nl][o4 + 0] = fmaxf(cv.x + m0, 0.f);   // relu(max)==max(relu)
        sm[nl][o4 + 1] = fmaxf(cv.y + m1, 0.f);
        sm[nl][o4 + 2] = fmaxf(cv.z + m2, 0.f);
        sm[nl][o4 + 3] = fmaxf(cv.w + m3, 0.f);
    }

    __syncthreads();

    // ---- transposed coalesced store ----
    float* ob = out + (size_t)b * C_OUT * N_PTS + n0;
    const int nn = lane & 31;
    const int oh = lane >> 5;
#pragma unroll
    for (int j = 0; j < 8; ++j) {
        const int o = wv * 16 + j * 2 + oh;
        ob[(size_t)o * N_PTS + nn] = sm[nn][o];   // 2x128B segments
    }
}

// ---------------------------------------------------------------------------
extern "C" void kernel_launch(void* const* d_in, const int* in_sizes, int n_in,
                              void* d_out, int out_size, void* d_ws, size_t ws_size,
                              hipStream_t stream)
{
    const float* x    = (const float*)d_in[0];
    const int*   eidx = (const int*)d_in[1];    // int64 in ref -> int32 here
    const float* w    = (const float*)d_in[2];  // (64, 128)
    const float* bias = (const float*)d_in[3];  // (64,)
    float*       out  = (float*)d_out;          // (8, 64, 64, 64) f32

    unsigned short* nbuf  = (unsigned short*)d_ws;                 // 4 MiB
    v8s*            wfrag = (v8s*)((char*)d_ws + (size_t)ROWS * C_OUT * 2);

    wprep_kernel<<<4, 256, 0, stream>>>(w, wfrag);
    proj_nbuf<<<ROWS / 64, 256, 0, stream>>>(x, wfrag, nbuf);
    gather_fused<<<B_SZ * (N_PTS / 32), 256, 0, stream>>>(x, wfrag, bias, eidx,
                                                          nbuf, out);
}